// Round 12
// baseline (1964.005 us; speedup 1.0000x reference)
//
#include <hip/hip_runtime.h>
#include <math.h>

#define N_ANCH 76725
#define SORT_N 4096
#define NBKT 1024
#define BBASE 0x3D40u

struct TrunkArgs {
  const float* in[2][5];
  float* out[2][5];
  const float* w[2];   // re-laid weights: w[head] + cog*2304*64 + (ci*9+tap)*64 + co_in_64
  const float* b[2];
};

struct WtrArgs {
  const float* src[2];  // original w[co][ci][tap] per head, one layer
  float* dst;           // wt2: [head][cog][2304][64]
};

struct Out2Args {
  const float* in[2][5];
  const float* w;       // transposed out-weights: [g][2304][16], trio at 4*wv
  const float* b[2];
  float* dst[2];
};

__device__ __forceinline__ int pick5(int l, int a, int b, int c, int d, int e) {
  int r = a;
  if (l == 1) r = b;
  if (l == 2) r = c;
  if (l == 3) r = d;
  if (l == 4) r = e;
  return r;
}

// 64-position tiling (8x8): 139 tiles (conv_out2)
__device__ __forceinline__ void tile_to_level(int tile, int& lvl, int& t) {
  int l = 0;
  if (tile >= 100) l = 1;
  if (tile >= 125) l = 2;
  if (tile >= 134) l = 3;
  if (tile >= 138) l = 4;
  lvl = l;
  t = tile - pick5(l, 0, 100, 125, 134, 138);
}

// async global->LDS, 16B per lane; dst is wave-uniform base, lane i lands at dst+16*i
__device__ __forceinline__ void glds16(const float* g, float* l) {
  __builtin_amdgcn_global_load_lds(
      (const __attribute__((address_space(1))) unsigned int*)g,
      (__attribute__((address_space(3))) unsigned int*)l, 16, 0, 0);
}

// ---------------- weight re-layout: w[co][ci][tap] -> wt2[head][cog][(ci*9+tap)][co64] ----------------
__global__ __launch_bounds__(256) void wtr_k(WtrArgs a) {
  __shared__ float tile[72][65];
  const int r0 = blockIdx.x * 72;   // 32 groups
  const int cog = blockIdx.y;       // 4 groups of 64 co
  const int co0 = cog * 64;
  const int head = blockIdx.z;
  const float* __restrict__ src = a.src[head];
  float* __restrict__ dst = a.dst + ((size_t)(head * 4 + cog) * 2304 + r0) * 64;
  const int tid = threadIdx.x;
  #pragma unroll
  for (int i = 0; i < 18; i++) {
    int e = tid + 256 * i;  // < 4608
    int co = e / 72;
    int r = e - co * 72;
    tile[r][co] = src[(size_t)(co0 + co) * 2304 + r0 + r];
  }
  __syncthreads();
  #pragma unroll
  for (int i = 0; i < 18; i++) {
    int e = tid + 256 * i;
    int r = e >> 6;
    int co = e & 63;
    dst[(size_t)r * 64 + co] = tile[r][co];
  }
}

// ---------------- output-conv weight transpose: -> wt2o[g][row=ci*9+tap][16] ----------------
__global__ __launch_bounds__(256) void wtro_k(const float* __restrict__ cls_ow,
                                              const float* __restrict__ reg_ow,
                                              float* __restrict__ dst) {
  int r = blockIdx.x * 256 + threadIdx.x;   // 0..2303
  if (r >= 2304) return;
  for (int g = 0; g < 5; g++) {
    #pragma unroll
    for (int s = 0; s < 16; s++) {
      int w = s >> 2, c = s & 3;
      float v = 0.f;
      if (w < 3 && c < 3) {
        int cl = 3 * w + c;
        v = (g == 0) ? cls_ow[(size_t)cl * 2304 + r]
                     : reg_ow[(size_t)((g - 1) * 9 + cl) * 2304 + r];
      }
      dst[((size_t)g * 2304 + r) * 16 + s] = v;
    }
  }
}

// ---------------- trunk conv: 256->256, 3x3, SAME, ReLU ----------------
// block tile: 128 pos (16 rows x 8 cols) x 64 co, BK=8, **128 threads**.
// thread: 8 pos (one row) x **8 co** -> per (ci,ty): 3 A-instrs + 6 W-b128 for
// 192 FMAs (21.3 FMA/LDS-instr, 2x R11). W via global_load_lds double-buffer;
// A via reg-prefetch double-buffer; one barrier per chunk.
// FMA order (ci asc, ty asc, tx asc) per output unchanged -> bit-exact.
__device__ __forceinline__ void a_load(const float* __restrict__ in, int ci0,
                                       int ty0, int tx0, int W, int HW, int tid,
                                       float a_reg[12]) {
  const float* inc = in + ci0 * HW;
  #pragma unroll
  for (int i = 0; i < 12; i++) {
    int e = tid + 128 * i;
    float v = 0.f;
    if (e < 1440) {
      int ci = e / 180;
      int rem = e - ci * 180;
      int yy = rem / 10;
      int xx = rem - yy * 10;
      int gy = ty0 + yy - 1, gx = tx0 + xx - 1;
      if ((unsigned)gy < (unsigned)W && (unsigned)gx < (unsigned)W)
        v = inc[ci * HW + gy * W + gx];
    }
    a_reg[i] = v;
  }
}

__device__ __forceinline__ void a_store(int tid, const float a_reg[12],
                                        float As[8][18][12]) {
  #pragma unroll
  for (int i = 0; i < 12; i++) {
    int e = tid + 128 * i;
    if (e < 1440) {
      int ci = e / 180;
      int rem = e - ci * 180;
      int yy = rem / 10;
      int xx = rem - yy * 10;
      As[ci][yy][xx] = a_reg[i];
    }
  }
}

__device__ __forceinline__ void stage_w(const float* __restrict__ wchunk,
                                        float* wbuf, int wv, int lane) {
  #pragma unroll
  for (int i = 0; i < 9; i++) {
    int j = wv + 2 * i;           // wave-uniform, covers 0..17 over 2 waves
    glds16(wchunk + j * 256 + lane * 4, wbuf + j * 256);
  }
}

__global__ __launch_bounds__(128) void conv_trunk(TrunkArgs args) {
  __shared__ float As[2][8][18][12];   // 2 x 6.75 KB
  __shared__ float Ws[2][72][64];      // 2 x 18 KB
  // 128-pos tiling: offsets {0,50,65,71,73,74}
  int l = 0;
  if (blockIdx.x >= 50) l = 1;
  if (blockIdx.x >= 65) l = 2;
  if (blockIdx.x >= 71) l = 3;
  if (blockIdx.x >= 73) l = 4;
  const int lvl = l;
  const int t = blockIdx.x - pick5(l, 0, 50, 65, 71, 73);
  const int W = 80 >> lvl;
  const int HW = W * W;
  const int tX = (W + 7) >> 3;
  const int ty0 = (t / tX) * 16, tx0 = (t % tX) * 8;
  const int head = blockIdx.z;
  const int co0 = blockIdx.y << 6;
  const float* __restrict__ in = args.in[head][lvl];
  float* __restrict__ out = args.out[head][lvl];
  const float* __restrict__ wsrc = args.w[head] + (size_t)blockIdx.y * 2304 * 64;
  const int tid = threadIdx.x;
  const int lane = tid & 63, wv = tid >> 6;   // 2 waves
  const int copg = tid & 7;                   // co octet
  const int ry = tid >> 3;                    // 0..15: row within tile
  const int co_sub = copg << 3;
  float acc[8][8] = {};                       // [pos][co]
  float a_reg[12];

  stage_w(wsrc, &Ws[0][0][0], wv, lane);
  a_load(in, 0, ty0, tx0, W, HW, tid, a_reg);
  a_store(tid, a_reg, As[0]);
  __syncthreads();

  for (int k = 0; k < 32; k++) {
    const int kb = k & 1;
    const bool more = k < 31;
    if (more) {
      stage_w(wsrc + (size_t)(k + 1) * 4608, &Ws[kb ^ 1][0][0], wv, lane);
      a_load(in, (k + 1) * 8, ty0, tx0, W, HW, tid, a_reg);
    }
    #pragma unroll 2
    for (int ci = 0; ci < 8; ci++) {
      #pragma unroll
      for (int ty = 0; ty < 3; ty++) {
        const float* ar = &As[kb][ci][ry + ty][0];
        float4 a0 = *(const float4*)ar;
        float4 a1 = *(const float4*)(ar + 4);
        float2 a2 = *(const float2*)(ar + 8);
        float a[10] = {a0.x, a0.y, a0.z, a0.w, a1.x, a1.y, a1.z, a1.w, a2.x, a2.y};
        #pragma unroll
        for (int tx = 0; tx < 3; tx++) {
          const float* wr = &Ws[kb][ci * 9 + ty * 3 + tx][co_sub];
          float4 w0 = *(const float4*)wr;
          float4 w1 = *(const float4*)(wr + 4);
          #pragma unroll
          for (int p = 0; p < 8; p++) {
            float av = a[tx + p];
            acc[p][0] = fmaf(av, w0.x, acc[p][0]);
            acc[p][1] = fmaf(av, w0.y, acc[p][1]);
            acc[p][2] = fmaf(av, w0.z, acc[p][2]);
            acc[p][3] = fmaf(av, w0.w, acc[p][3]);
            acc[p][4] = fmaf(av, w1.x, acc[p][4]);
            acc[p][5] = fmaf(av, w1.y, acc[p][5]);
            acc[p][6] = fmaf(av, w1.z, acc[p][6]);
            acc[p][7] = fmaf(av, w1.w, acc[p][7]);
          }
        }
      }
    }
    if (more) {
      a_store(tid, a_reg, As[kb ^ 1]);
      __syncthreads();
    }
  }
  const float4 b0 = *(const float4*)&args.b[head][co0 + co_sub];
  const float4 b1 = *(const float4*)&args.b[head][co0 + co_sub + 4];
  const float bias[8] = {b0.x, b0.y, b0.z, b0.w, b1.x, b1.y, b1.z, b1.w};
  const int oy = ty0 + ry;
  if (oy < W) {
    #pragma unroll
    for (int p = 0; p < 8; p++) {
      int ox = tx0 + p;
      if (ox < W) {
        int base = oy * W + ox;
        #pragma unroll
        for (int c = 0; c < 8; c++)
          out[(co0 + co_sub + c) * HW + base] = fmaxf(acc[p][c] + bias[c], 0.f);
      }
    }
  }
}

// ---------------- fused output convs: reg-prefetch pipeline, one barrier/chunk ----------------
__device__ __forceinline__ void ao_load(const float* __restrict__ in, int ci0,
                                        int ty0, int tx0, int W, int HW, int tid,
                                        float a_reg[5]) {
  const float* inc = in + ci0 * HW;
  #pragma unroll
  for (int i = 0; i < 5; i++) {
    int e = tid + 192 * i;
    float v = 0.f;
    if (e < 800) {
      int ci = e / 100;
      int rem = e - ci * 100;
      int yy = rem / 10;
      int xx = rem - yy * 10;
      int gy = ty0 + yy - 1, gx = tx0 + xx - 1;
      if ((unsigned)gy < (unsigned)W && (unsigned)gx < (unsigned)W)
        v = inc[ci * HW + gy * W + gx];
    }
    a_reg[i] = v;
  }
}

__device__ __forceinline__ void ao_store(int tid, const float a_reg[5],
                                         float As[8][10][12]) {
  #pragma unroll
  for (int i = 0; i < 5; i++) {
    int e = tid + 192 * i;
    if (e < 800) {
      int ci = e / 100;
      int rem = e - ci * 100;
      int yy = rem / 10;
      int xx = rem - yy * 10;
      As[ci][yy][xx] = a_reg[i];
    }
  }
}

__global__ __launch_bounds__(192) void conv_out2(Out2Args args) {
  __shared__ float As[2][8][10][12];
  __shared__ __align__(16) float Wg[2][8][9][16];
  int lvl, t;
  tile_to_level(blockIdx.x, lvl, t);
  const int g = blockIdx.y;
  const int head = (g == 0) ? 0 : 1;
  const int co0 = (g == 0) ? 0 : (g - 1) * 9;
  const int W = 80 >> lvl;
  const int HW = W * W;
  const int tX = (W + 7) >> 3;
  const int ty0 = (t / tX) * 8, tx0 = (t % tX) * 8;
  const float* __restrict__ in = args.in[head][lvl];
  const float* __restrict__ wg = args.w + (size_t)g * 2304 * 16;
  const int tid = threadIdx.x;
  const int lane = tid & 63;
  const int wv = tid >> 6;
  const int y = lane >> 3, x = lane & 7;
  float acc0 = 0.f, acc1 = 0.f, acc2 = 0.f;
  float a_reg[5];
  float4 w_reg[2];

  ao_load(in, 0, ty0, tx0, W, HW, tid, a_reg);
  {
    const float4* wsrc4 = (const float4*)wg;
    #pragma unroll
    for (int i = 0; i < 2; i++) {
      int e = tid + 192 * i;
      if (e < 288) w_reg[i] = wsrc4[e];
    }
  }
  ao_store(tid, a_reg, As[0]);
  {
    float4* wdst4 = (float4*)&Wg[0][0][0][0];
    #pragma unroll
    for (int i = 0; i < 2; i++) {
      int e = tid + 192 * i;
      if (e < 288) wdst4[e] = w_reg[i];
    }
  }
  __syncthreads();

  for (int k = 0; k < 32; k++) {
    const int kb = k & 1;
    const bool more = k < 31;
    if (more) {
      ao_load(in, (k + 1) * 8, ty0, tx0, W, HW, tid, a_reg);
      const float4* wsrc4 = (const float4*)(wg + (size_t)(k + 1) * 1152);
      #pragma unroll
      for (int i = 0; i < 2; i++) {
        int e = tid + 192 * i;
        if (e < 288) w_reg[i] = wsrc4[e];
      }
    }
    #pragma unroll 2
    for (int ci = 0; ci < 8; ci++) {
      #pragma unroll
      for (int ty = 0; ty < 3; ty++) {
        float a0 = As[kb][ci][y + ty][x + 0];
        float a1 = As[kb][ci][y + ty][x + 1];
        float a2 = As[kb][ci][y + ty][x + 2];
        #pragma unroll
        for (int tx = 0; tx < 3; tx++) {
          float av = (tx == 0) ? a0 : (tx == 1) ? a1 : a2;
          float4 w4 = *(const float4*)&Wg[kb][ci][ty * 3 + tx][4 * wv];
          acc0 = fmaf(av, w4.x, acc0);
          acc1 = fmaf(av, w4.y, acc1);
          acc2 = fmaf(av, w4.z, acc2);
        }
      }
    }
    if (more) {
      ao_store(tid, a_reg, As[kb ^ 1]);
      float4* wdst4 = (float4*)&Wg[kb ^ 1][0][0][0];
      #pragma unroll
      for (int i = 0; i < 2; i++) {
        int e = tid + 192 * i;
        if (e < 288) wdst4[e] = w_reg[i];
      }
      __syncthreads();
    }
  }
  const int oy = ty0 + y, ox = tx0 + x;
  if (oy < W && ox < W) {
    const int cell = oy * W + ox;
    const int aoff = pick5(lvl, 0, 57600, 72000, 75600, 76500);
    float* dst = args.dst[head];
    const float* bias = args.b[head];
    #pragma unroll
    for (int c = 0; c < 3; c++) {
      int co = co0 + 3 * wv + c;
      float v = ((c == 0) ? acc0 : (c == 1) ? acc1 : acc2) + bias[co];
      if (head == 0) {
        v = 1.f / (1.f + expf(-v));
        dst[aoff + cell * 9 + co] = v;
      } else {
        dst[(size_t)aoff * 4 + cell * 36 + co] = v;
      }
    }
  }
}

// ---------------- init / decode (unchanged) ----------------
__global__ void init_k(int* meta) {
  int i = blockIdx.x * 256 + threadIdx.x;
  if (i < 1 + NBKT) meta[i] = 0;
}

__global__ __launch_bounds__(256) void decode_k(const float* __restrict__ scores,
                                                const float* __restrict__ regs,
                                                float* cand_s, float4* cand_b,
                                                int* cand_n, int* meta) {
  int n = blockIdx.x * 256 + threadIdx.x;
  if (n >= N_ANCH) return;
  int lvl = 0;
  if (n >= 57600) lvl = 1;
  if (n >= 72000) lvl = 2;
  if (n >= 75600) lvl = 3;
  if (n >= 76500) lvl = 4;
  const int aoff = pick5(lvl, 0, 57600, 72000, 75600, 76500);
  const int W = 80 >> lvl;
  int r = n - aoff;
  int a = r % 9;
  int cell = r / 9;
  int x = cell % W, y = cell / W;
  double stride = (double)(8 << lvl);
  double base = (double)(32 << lvl);
  int si = a % 3, ri = a / 3;
  double s = (si == 0) ? 1.0 : (si == 1) ? 1.2599210498948731648 : 1.5874010519681994748;
  double ratio = (ri == 0) ? 0.5 : (ri == 1) ? 1.0 : 2.0;
  double ws0 = base * s;
  double area = ws0 * ws0;
  double w = sqrt(area / ratio);
  double h = w * ratio;
  double cx = ((double)x + 0.5) * stride;
  double cy = ((double)y + 0.5) * stride;
  float ax1 = (float)(cx - 0.5 * w);
  float ay1 = (float)(cy - 0.5 * h);
  float ax2 = (float)(cx + (w - 0.5 * w));
  float ay2 = (float)(cy + (h - 0.5 * h));
  float4 rg = ((const float4*)regs)[n];
  float aw = ax2 - ax1, ah = ay2 - ay1;
  float acx = ax1 + 0.5f * aw, acy = ay1 + 0.5f * ah;
  float pcx = acx + rg.x * 0.1f * aw;
  float pcy = acy + rg.y * 0.1f * ah;
  float pw = expf(rg.z * 0.2f) * aw;
  float ph = expf(rg.w * 0.2f) * ah;
  float x1 = pcx - 0.5f * pw, y1 = pcy - 0.5f * ph;
  float x2 = pcx + 0.5f * pw, y2 = pcy + 0.5f * ph;
  x1 = fminf(fmaxf(x1, 0.f), 640.f);
  y1 = fminf(fmaxf(y1, 0.f), 640.f);
  x2 = fminf(fmaxf(x2, 0.f), 640.f);
  y2 = fminf(fmaxf(y2, 0.f), 640.f);
  float sc = scores[n];
  if (sc > 0.05f) {
    int p = atomicAdd(&meta[0], 1);
    cand_s[p] = sc;
    cand_b[p] = make_float4(x1, y1, x2, y2);
    cand_n[p] = n;
    unsigned int sb = __float_as_uint(sc);
    int bk = (int)(sb >> 16) - (int)BBASE;
    bk = max(0, min(NBKT - 1, bk));
    atomicAdd(&meta[1 + bk], 1);
  }
}

// ---------------- sort-based exact greedy NMS (unchanged from R10) ----------------
__global__ __launch_bounds__(1024) void nms2_k(const float* __restrict__ cs,
                                               const float4* __restrict__ cb,
                                               const int* __restrict__ cn,
                                               const int* __restrict__ meta,
                                               float* __restrict__ out) {
  __shared__ unsigned long long skey[SORT_N];
  __shared__ int sidx[SORT_N];
  __shared__ int suf[NBKT];
  __shared__ float kx1[300], ky1[300], kx2[300], ky2[300], kar[300];
  __shared__ int sh_i[8];
  const int tid = threadIdx.x;
  const int m = min(meta[0], N_ANCH);

  for (int b = tid; b < NBKT; b += 1024) suf[b] = meta[1 + b];
  __syncthreads();
  for (int off = 1; off < NBKT; off <<= 1) {
    int v0 = suf[tid] + ((tid + off < NBKT) ? suf[tid + off] : 0);
    __syncthreads();
    suf[tid] = v0;
    __syncthreads();
  }

  int nk = 0;
  unsigned long long hi64 = ~0ULL;
  int processed = 0;

  while (nk < 300 && processed < m) {
    int base = 0;
    if (hi64 != ~0ULL) {
      if (tid == 0) sh_i[4] = 0;
      __syncthreads();
      int c = 0;
      for (int j = tid; j < m; j += 1024) {
        unsigned long long K = ((unsigned long long)__float_as_uint(cs[j]) << 32) |
                               (unsigned int)(~cn[j]);
        if (K >= hi64) c++;
      }
      atomicAdd(&sh_i[4], c);
      __syncthreads();
      base = sh_i[4];
      __syncthreads();
    }
    if (tid == 0) sh_i[3] = NBKT + 1;
    __syncthreads();
    {
      int T = tid;
      unsigned long long lo =
          (T == 0) ? 0ULL : ((unsigned long long)(((unsigned)T + BBASE) << 16) << 32);
      int c = suf[T] - base;
      if (lo < hi64 && c >= 1 && c <= SORT_N) atomicMin(&sh_i[3], T);
    }
    __syncthreads();
    int T = sh_i[3];
    __syncthreads();
    unsigned long long lo64;
    if (T <= NBKT) {
      lo64 = (T == 0) ? 0ULL : ((unsigned long long)(((unsigned)T + BBASE) << 16) << 32);
    } else {
      unsigned long long L = 0, H = hi64;
      while (H - L > 1) {
        unsigned long long mid = L + ((H - L) >> 1);
        if (tid == 0) sh_i[4] = 0;
        __syncthreads();
        int c = 0;
        for (int j = tid; j < m; j += 1024) {
          unsigned long long K = ((unsigned long long)__float_as_uint(cs[j]) << 32) |
                                 (unsigned int)(~cn[j]);
          if (K >= mid && K < hi64) c++;
        }
        atomicAdd(&sh_i[4], c);
        __syncthreads();
        int cc = sh_i[4];
        __syncthreads();
        if (cc > SORT_N) L = mid; else H = mid;
      }
      lo64 = H;
    }
    if (tid == 0) sh_i[0] = 0;
    __syncthreads();
    for (int j = tid; j < m; j += 1024) {
      unsigned long long K = ((unsigned long long)__float_as_uint(cs[j]) << 32) |
                             (unsigned int)(~cn[j]);
      if (K >= lo64 && K < hi64) {
        int p = atomicAdd(&sh_i[0], 1);
        if (p < SORT_N) { skey[p] = K; sidx[p] = j; }
      }
    }
    __syncthreads();
    int bn = min(sh_i[0], SORT_N);
    __syncthreads();
    for (int p = bn + tid; p < SORT_N; p += 1024) { skey[p] = 0; sidx[p] = 0; }
    __syncthreads();
    for (int k = 2; k <= SORT_N; k <<= 1) {
      for (int jj = k >> 1; jj > 0; jj >>= 1) {
        for (int i = tid; i < SORT_N; i += 1024) {
          int l2 = i ^ jj;
          if (l2 > i) {
            unsigned long long a = skey[i], b2 = skey[l2];
            bool desc = ((i & k) == 0);
            if ((a < b2) == desc) {
              skey[i] = b2; skey[l2] = a;
              int t2 = sidx[i]; sidx[i] = sidx[l2]; sidx[l2] = t2;
            }
          }
        }
        __syncthreads();
      }
    }
    float4 pb0 = (bn > 0) ? cb[sidx[0]] : make_float4(0.f, 0.f, 0.f, 0.f);
    float4 pb1 = (bn > 1) ? cb[sidx[1]] : make_float4(0.f, 0.f, 0.f, 0.f);
    int pos = 0;
    while (pos < bn && nk < 300) {
      float4 c0 = pb0, c1 = pb1;
      const bool has1 = (pos + 1 < bn);
      unsigned long long K0 = skey[pos];
      unsigned long long K1 = has1 ? skey[pos + 1] : 0ULL;
      if (pos + 2 < bn) pb0 = cb[sidx[pos + 2]];
      if (pos + 3 < bn) pb1 = cb[sidx[pos + 3]];
      if (tid == 0) { sh_i[1] = 0; sh_i[2] = 0; }
      __syncthreads();
      float ar0 = (c0.z - c0.x) * (c0.w - c0.y);
      float ar1 = (c1.z - c1.x) * (c1.w - c1.y);
      if (tid < nk) {
        float qx1 = kx1[tid], qy1 = ky1[tid], qx2 = kx2[tid], qy2 = ky2[tid], qa = kar[tid];
        float xx1 = fmaxf(qx1, c0.x), yy1 = fmaxf(qy1, c0.y);
        float xx2 = fminf(qx2, c0.z), yy2 = fminf(qy2, c0.w);
        float inter = fmaxf(xx2 - xx1, 0.f) * fmaxf(yy2 - yy1, 0.f);
        if (inter / (ar0 + qa - inter + 1e-8f) > 0.5f) sh_i[1] = 1;
        if (has1) {
          float ux1 = fmaxf(qx1, c1.x), uy1 = fmaxf(qy1, c1.y);
          float ux2 = fminf(qx2, c1.z), uy2 = fminf(qy2, c1.w);
          float inter1 = fmaxf(ux2 - ux1, 0.f) * fmaxf(uy2 - uy1, 0.f);
          if (inter1 / (ar1 + qa - inter1 + 1e-8f) > 0.5f) sh_i[2] = 1;
        }
      }
      __syncthreads();
      bool k0 = (sh_i[1] == 0);
      float px1 = fmaxf(c0.x, c1.x), py1 = fmaxf(c0.y, c1.y);
      float px2 = fminf(c0.z, c1.z), py2 = fminf(c0.w, c1.w);
      float pint = fmaxf(px2 - px1, 0.f) * fmaxf(py2 - py1, 0.f);
      bool p01 = (pint / (ar1 + ar0 - pint + 1e-8f)) > 0.5f;
      bool k1 = has1 && (sh_i[2] == 0) && !(k0 && p01);
      if (k0) {
        if (tid == 0) {
          kx1[nk] = c0.x; ky1[nk] = c0.y; kx2[nk] = c0.z; ky2[nk] = c0.w; kar[nk] = ar0;
          out[nk] = __uint_as_float((unsigned int)(K0 >> 32));
          out[300 + nk] = 0.0f;
          out[600 + 4 * nk + 0] = c0.x;
          out[600 + 4 * nk + 1] = c0.y;
          out[600 + 4 * nk + 2] = c0.z;
          out[600 + 4 * nk + 3] = c0.w;
        }
        nk++;
      }
      if (nk < 300 && k1) {
        if (tid == 0) {
          kx1[nk] = c1.x; ky1[nk] = c1.y; kx2[nk] = c1.z; ky2[nk] = c1.w; kar[nk] = ar1;
          out[nk] = __uint_as_float((unsigned int)(K1 >> 32));
          out[300 + nk] = 0.0f;
          out[600 + 4 * nk + 0] = c1.x;
          out[600 + 4 * nk + 1] = c1.y;
          out[600 + 4 * nk + 2] = c1.z;
          out[600 + 4 * nk + 3] = c1.w;
        }
        nk++;
      }
      pos += 2;
    }
    processed = base + bn;
    hi64 = lo64;
  }
  __syncthreads();
  for (int r = nk + tid; r < 300; r += 1024) {
    out[r] = 0.f;
    out[300 + r] = -1.f;
    out[600 + 4 * r + 0] = 0.f;
    out[600 + 4 * r + 1] = 0.f;
    out[600 + 4 * r + 2] = 0.f;
    out[600 + 4 * r + 3] = 0.f;
  }
}

// ---------------- host ----------------
extern "C" void kernel_launch(void* const* d_in, const int* in_sizes, int n_in,
                              void* d_out, int out_size, void* d_ws, size_t ws_size,
                              hipStream_t stream) {
  (void)in_sizes; (void)n_in; (void)out_size; (void)ws_size;
  const float* feats[5];
  for (int l = 0; l < 5; l++) feats[l] = (const float*)d_in[1 + l];
  const float* cls_w = (const float*)d_in[6];
  const float* cls_b = (const float*)d_in[7];
  const float* cls_ow = (const float*)d_in[8];
  const float* cls_ob = (const float*)d_in[9];
  const float* reg_w = (const float*)d_in[10];
  const float* reg_b = (const float*)d_in[11];
  const float* reg_ow = (const float*)d_in[12];
  const float* reg_ob = (const float*)d_in[13];

  static const int AOFF[5] = {0, 1638400, 2048000, 2150400, 2176000}; // 256*cumHW
  const size_t ACT = 2182400;  // 256*8525 floats per head

  float* ws = (float*)d_ws;
  float* bufA = ws;                       // 2*ACT
  float* bufB = bufA + 2 * ACT;           // 2*ACT
  float* scores = bufB + 2 * ACT;         // 76736 (padded)
  float* regs = scores + 76736;           // 306912 (padded)
  float* cand_s = regs + 306912;          // 76736
  float* cand_b = cand_s + 76736;         // 306944
  int* cand_n = (int*)(cand_b + 306944);  // 76736 ints
  int* meta = cand_n + 76736;             // [0]=cnt, [1..NBKT]=hist
  float* wt = (float*)(meta + 1032);      // 2 heads x 4 cog x 2304 x 64
  float* wt2o = wt + 2 * 4 * 2304 * 64;   // 5 x 2304 x 16

  float* bufs[2] = {bufA, bufB};
  TrunkArgs ta;
  WtrArgs wa;
  wa.dst = wt;
  wtro_k<<<dim3(9), dim3(256), 0, stream>>>(cls_ow, reg_ow, wt2o);
  for (int layer = 0; layer < 4; layer++) {
    wa.src[0] = cls_w + (size_t)layer * 589824;
    wa.src[1] = reg_w + (size_t)layer * 589824;
    wtr_k<<<dim3(32, 4, 2), dim3(256), 0, stream>>>(wa);
    for (int h = 0; h < 2; h++) {
      ta.w[h] = wt + (size_t)h * 4 * 2304 * 64;
      ta.b[h] = (h ? reg_b : cls_b) + layer * 256;
      for (int l = 0; l < 5; l++) {
        ta.out[h][l] = bufs[layer & 1] + h * ACT + AOFF[l];
        ta.in[h][l] = (layer == 0) ? feats[l] : (const float*)(bufs[(layer - 1) & 1] + h * ACT + AOFF[l]);
      }
    }
    conv_trunk<<<dim3(74, 4, 2), dim3(128), 0, stream>>>(ta);
  }

  Out2Args oa;
  for (int l = 0; l < 5; l++) {
    oa.in[0][l] = bufB + 0 * ACT + AOFF[l];
    oa.in[1][l] = bufB + 1 * ACT + AOFF[l];
  }
  oa.w = wt2o;
  oa.b[0] = cls_ob; oa.b[1] = reg_ob;
  oa.dst[0] = scores; oa.dst[1] = regs;
  conv_out2<<<dim3(139, 5), dim3(192), 0, stream>>>(oa);

  init_k<<<dim3(5), dim3(256), 0, stream>>>(meta);
  decode_k<<<dim3((N_ANCH + 255) / 256), dim3(256), 0, stream>>>(scores, regs, cand_s,
                                                                 (float4*)cand_b, cand_n, meta);
  nms2_k<<<dim3(1), dim3(1024), 0, stream>>>(cand_s, (const float4*)cand_b, cand_n, meta,
                                             (float*)d_out);
}

// Round 13
// 1727.320 us; speedup vs baseline: 1.1370x; 1.1370x over previous
//
#include <hip/hip_runtime.h>
#include <math.h>

#define N_ANCH 76725
#define SORT_N 4096
#define NBKT 1024
#define BBASE 0x3D40u

struct TrunkArgs {
  const float* in[2][5];
  float* out[2][5];
  const float* w[2];   // re-laid weights: w[head] + cog*2304*64 + (ci*9+tap)*64 + co_in_64
  const float* b[2];
};

struct WtrArgs {
  const float* src[2];  // original w[co][ci][tap] per head, one layer
  float* dst;           // wt2: [head][cog][2304][64]
};

struct Out2Args {
  const float* in[2][5];
  const float* w;       // transposed out-weights: [g][2304][16], trio at 4*wv
  const float* b[2];
  float* dst[2];
};

__device__ __forceinline__ int pick5(int l, int a, int b, int c, int d, int e) {
  int r = a;
  if (l == 1) r = b;
  if (l == 2) r = c;
  if (l == 3) r = d;
  if (l == 4) r = e;
  return r;
}

// 64-position tiling (8x8): 139 tiles (conv_out2)
__device__ __forceinline__ void tile_to_level(int tile, int& lvl, int& t) {
  int l = 0;
  if (tile >= 100) l = 1;
  if (tile >= 125) l = 2;
  if (tile >= 134) l = 3;
  if (tile >= 138) l = 4;
  lvl = l;
  t = tile - pick5(l, 0, 100, 125, 134, 138);
}

// async global->LDS, 16B per lane; dst is wave-uniform base, lane i lands at dst+16*i
__device__ __forceinline__ void glds16(const float* g, float* l) {
  __builtin_amdgcn_global_load_lds(
      (const __attribute__((address_space(1))) unsigned int*)g,
      (__attribute__((address_space(3))) unsigned int*)l, 16, 0, 0);
}

// ---------------- weight re-layout: w[co][ci][tap] -> wt2[head][cog][(ci*9+tap)][co64] ----------------
__global__ __launch_bounds__(256) void wtr_k(WtrArgs a) {
  __shared__ float tile[72][65];
  const int r0 = blockIdx.x * 72;   // 32 groups
  const int cog = blockIdx.y;       // 4 groups of 64 co
  const int co0 = cog * 64;
  const int head = blockIdx.z;
  const float* __restrict__ src = a.src[head];
  float* __restrict__ dst = a.dst + ((size_t)(head * 4 + cog) * 2304 + r0) * 64;
  const int tid = threadIdx.x;
  #pragma unroll
  for (int i = 0; i < 18; i++) {
    int e = tid + 256 * i;  // < 4608
    int co = e / 72;
    int r = e - co * 72;
    tile[r][co] = src[(size_t)(co0 + co) * 2304 + r0 + r];
  }
  __syncthreads();
  #pragma unroll
  for (int i = 0; i < 18; i++) {
    int e = tid + 256 * i;
    int r = e >> 6;
    int co = e & 63;
    dst[(size_t)r * 64 + co] = tile[r][co];
  }
}

// ---------------- output-conv weight transpose: -> wt2o[g][row=ci*9+tap][16] ----------------
__global__ __launch_bounds__(256) void wtro_k(const float* __restrict__ cls_ow,
                                              const float* __restrict__ reg_ow,
                                              float* __restrict__ dst) {
  int r = blockIdx.x * 256 + threadIdx.x;   // 0..2303
  if (r >= 2304) return;
  for (int g = 0; g < 5; g++) {
    #pragma unroll
    for (int s = 0; s < 16; s++) {
      int w = s >> 2, c = s & 3;
      float v = 0.f;
      if (w < 3 && c < 3) {
        int cl = 3 * w + c;
        v = (g == 0) ? cls_ow[(size_t)cl * 2304 + r]
                     : reg_ow[(size_t)((g - 1) * 9 + cl) * 2304 + r];
      }
      dst[((size_t)g * 2304 + r) * 16 + s] = v;
    }
  }
}

// ---------------- trunk conv: R9/R11 proven config (256 thr, 8pos x 4co) ----------------
__device__ __forceinline__ void a_load(const float* __restrict__ in, int ci0,
                                       int ty0, int tx0, int W, int HW, int tid,
                                       float a_reg[6]) {
  const float* inc = in + ci0 * HW;
  #pragma unroll
  for (int i = 0; i < 6; i++) {
    int e = tid + 256 * i;
    float v = 0.f;
    if (e < 1440) {
      int ci = e / 180;
      int rem = e - ci * 180;
      int yy = rem / 10;
      int xx = rem - yy * 10;
      int gy = ty0 + yy - 1, gx = tx0 + xx - 1;
      if ((unsigned)gy < (unsigned)W && (unsigned)gx < (unsigned)W)
        v = inc[ci * HW + gy * W + gx];
    }
    a_reg[i] = v;
  }
}

__device__ __forceinline__ void a_store(int tid, const float a_reg[6],
                                        float As[8][18][12]) {
  #pragma unroll
  for (int i = 0; i < 6; i++) {
    int e = tid + 256 * i;
    if (e < 1440) {
      int ci = e / 180;
      int rem = e - ci * 180;
      int yy = rem / 10;
      int xx = rem - yy * 10;
      As[ci][yy][xx] = a_reg[i];
    }
  }
}

__device__ __forceinline__ void stage_w(const float* __restrict__ wchunk,
                                        float* wbuf, int wv, int lane) {
  #pragma unroll
  for (int i = 0; i < 5; i++) {
    int j = wv + 4 * i;           // wave-uniform
    if (j < 18) glds16(wchunk + j * 256 + lane * 4, wbuf + j * 256);
  }
}

__global__ __launch_bounds__(256) void conv_trunk(TrunkArgs args) {
  __shared__ float As[2][8][18][12];   // 2 x 6.75 KB
  __shared__ float Ws[2][72][64];      // 2 x 18 KB
  int l = 0;
  if (blockIdx.x >= 50) l = 1;
  if (blockIdx.x >= 65) l = 2;
  if (blockIdx.x >= 71) l = 3;
  if (blockIdx.x >= 73) l = 4;
  const int lvl = l;
  const int t = blockIdx.x - pick5(l, 0, 50, 65, 71, 73);
  const int W = 80 >> lvl;
  const int HW = W * W;
  const int tX = (W + 7) >> 3;
  const int ty0 = (t / tX) * 16, tx0 = (t % tX) * 8;
  const int head = blockIdx.z;
  const int co0 = blockIdx.y << 6;
  const float* __restrict__ in = args.in[head][lvl];
  float* __restrict__ out = args.out[head][lvl];
  const float* __restrict__ wsrc = args.w[head] + (size_t)blockIdx.y * 2304 * 64;
  const int tid = threadIdx.x;
  const int lane = tid & 63, wv = tid >> 6;
  const int cop = tid & 15;
  const int ry = tid >> 4;
  const int co_sub = cop << 2;
  float acc[8][4] = {};
  float a_reg[6];

  stage_w(wsrc, &Ws[0][0][0], wv, lane);
  a_load(in, 0, ty0, tx0, W, HW, tid, a_reg);
  a_store(tid, a_reg, As[0]);
  __syncthreads();

  for (int k = 0; k < 32; k++) {
    const int kb = k & 1;
    const bool more = k < 31;
    if (more) {
      stage_w(wsrc + (size_t)(k + 1) * 4608, &Ws[kb ^ 1][0][0], wv, lane);
      a_load(in, (k + 1) * 8, ty0, tx0, W, HW, tid, a_reg);
    }
    #pragma unroll 2
    for (int ci = 0; ci < 8; ci++) {
      #pragma unroll
      for (int ty = 0; ty < 3; ty++) {
        const float* ar = &As[kb][ci][ry + ty][0];
        float4 a0 = *(const float4*)ar;
        float4 a1 = *(const float4*)(ar + 4);
        float2 a2 = *(const float2*)(ar + 8);
        float a[10] = {a0.x, a0.y, a0.z, a0.w, a1.x, a1.y, a1.z, a1.w, a2.x, a2.y};
        #pragma unroll
        for (int tx = 0; tx < 3; tx++) {
          const float* wr = &Ws[kb][ci * 9 + ty * 3 + tx][co_sub];
          float4 wvv = *(const float4*)wr;
          #pragma unroll
          for (int p = 0; p < 8; p++) {
            acc[p][0] = fmaf(a[tx + p], wvv.x, acc[p][0]);
            acc[p][1] = fmaf(a[tx + p], wvv.y, acc[p][1]);
            acc[p][2] = fmaf(a[tx + p], wvv.z, acc[p][2]);
            acc[p][3] = fmaf(a[tx + p], wvv.w, acc[p][3]);
          }
        }
      }
    }
    if (more) {
      a_store(tid, a_reg, As[kb ^ 1]);
      __syncthreads();
    }
  }
  const float4 bias = *(const float4*)&args.b[head][co0 + co_sub];
  const int oy = ty0 + ry;
  if (oy < W) {
    #pragma unroll
    for (int p = 0; p < 8; p++) {
      int ox = tx0 + p;
      if (ox < W) {
        int base = oy * W + ox;
        out[(co0 + co_sub + 0) * HW + base] = fmaxf(acc[p][0] + bias.x, 0.f);
        out[(co0 + co_sub + 1) * HW + base] = fmaxf(acc[p][1] + bias.y, 0.f);
        out[(co0 + co_sub + 2) * HW + base] = fmaxf(acc[p][2] + bias.z, 0.f);
        out[(co0 + co_sub + 3) * HW + base] = fmaxf(acc[p][3] + bias.w, 0.f);
      }
    }
  }
}

// ---------------- fused output convs: reg-prefetch pipeline (R12, kept) ----------------
__device__ __forceinline__ void ao_load(const float* __restrict__ in, int ci0,
                                        int ty0, int tx0, int W, int HW, int tid,
                                        float a_reg[5]) {
  const float* inc = in + ci0 * HW;
  #pragma unroll
  for (int i = 0; i < 5; i++) {
    int e = tid + 192 * i;
    float v = 0.f;
    if (e < 800) {
      int ci = e / 100;
      int rem = e - ci * 100;
      int yy = rem / 10;
      int xx = rem - yy * 10;
      int gy = ty0 + yy - 1, gx = tx0 + xx - 1;
      if ((unsigned)gy < (unsigned)W && (unsigned)gx < (unsigned)W)
        v = inc[ci * HW + gy * W + gx];
    }
    a_reg[i] = v;
  }
}

__device__ __forceinline__ void ao_store(int tid, const float a_reg[5],
                                         float As[8][10][12]) {
  #pragma unroll
  for (int i = 0; i < 5; i++) {
    int e = tid + 192 * i;
    if (e < 800) {
      int ci = e / 100;
      int rem = e - ci * 100;
      int yy = rem / 10;
      int xx = rem - yy * 10;
      As[ci][yy][xx] = a_reg[i];
    }
  }
}

__global__ __launch_bounds__(192) void conv_out2(Out2Args args) {
  __shared__ float As[2][8][10][12];
  __shared__ __align__(16) float Wg[2][8][9][16];
  int lvl, t;
  tile_to_level(blockIdx.x, lvl, t);
  const int g = blockIdx.y;
  const int head = (g == 0) ? 0 : 1;
  const int co0 = (g == 0) ? 0 : (g - 1) * 9;
  const int W = 80 >> lvl;
  const int HW = W * W;
  const int tX = (W + 7) >> 3;
  const int ty0 = (t / tX) * 8, tx0 = (t % tX) * 8;
  const float* __restrict__ in = args.in[head][lvl];
  const float* __restrict__ wg = args.w + (size_t)g * 2304 * 16;
  const int tid = threadIdx.x;
  const int lane = tid & 63;
  const int wv = tid >> 6;
  const int y = lane >> 3, x = lane & 7;
  float acc0 = 0.f, acc1 = 0.f, acc2 = 0.f;
  float a_reg[5];
  float4 w_reg[2];

  ao_load(in, 0, ty0, tx0, W, HW, tid, a_reg);
  {
    const float4* wsrc4 = (const float4*)wg;
    #pragma unroll
    for (int i = 0; i < 2; i++) {
      int e = tid + 192 * i;
      if (e < 288) w_reg[i] = wsrc4[e];
    }
  }
  ao_store(tid, a_reg, As[0]);
  {
    float4* wdst4 = (float4*)&Wg[0][0][0][0];
    #pragma unroll
    for (int i = 0; i < 2; i++) {
      int e = tid + 192 * i;
      if (e < 288) wdst4[e] = w_reg[i];
    }
  }
  __syncthreads();

  for (int k = 0; k < 32; k++) {
    const int kb = k & 1;
    const bool more = k < 31;
    if (more) {
      ao_load(in, (k + 1) * 8, ty0, tx0, W, HW, tid, a_reg);
      const float4* wsrc4 = (const float4*)(wg + (size_t)(k + 1) * 1152);
      #pragma unroll
      for (int i = 0; i < 2; i++) {
        int e = tid + 192 * i;
        if (e < 288) w_reg[i] = wsrc4[e];
      }
    }
    #pragma unroll 2
    for (int ci = 0; ci < 8; ci++) {
      #pragma unroll
      for (int ty = 0; ty < 3; ty++) {
        float a0 = As[kb][ci][y + ty][x + 0];
        float a1 = As[kb][ci][y + ty][x + 1];
        float a2 = As[kb][ci][y + ty][x + 2];
        #pragma unroll
        for (int tx = 0; tx < 3; tx++) {
          float av = (tx == 0) ? a0 : (tx == 1) ? a1 : a2;
          float4 w4 = *(const float4*)&Wg[kb][ci][ty * 3 + tx][4 * wv];
          acc0 = fmaf(av, w4.x, acc0);
          acc1 = fmaf(av, w4.y, acc1);
          acc2 = fmaf(av, w4.z, acc2);
        }
      }
    }
    if (more) {
      ao_store(tid, a_reg, As[kb ^ 1]);
      float4* wdst4 = (float4*)&Wg[kb ^ 1][0][0][0];
      #pragma unroll
      for (int i = 0; i < 2; i++) {
        int e = tid + 192 * i;
        if (e < 288) wdst4[e] = w_reg[i];
      }
      __syncthreads();
    }
  }
  const int oy = ty0 + y, ox = tx0 + x;
  if (oy < W && ox < W) {
    const int cell = oy * W + ox;
    const int aoff = pick5(lvl, 0, 57600, 72000, 75600, 76500);
    float* dst = args.dst[head];
    const float* bias = args.b[head];
    #pragma unroll
    for (int c = 0; c < 3; c++) {
      int co = co0 + 3 * wv + c;
      float v = ((c == 0) ? acc0 : (c == 1) ? acc1 : acc2) + bias[co];
      if (head == 0) {
        v = 1.f / (1.f + expf(-v));
        dst[aoff + cell * 9 + co] = v;
      } else {
        dst[(size_t)aoff * 4 + cell * 36 + co] = v;
      }
    }
  }
}

// ---------------- init / decode (unchanged) ----------------
__global__ void init_k(int* meta) {
  int i = blockIdx.x * 256 + threadIdx.x;
  if (i < 1 + NBKT) meta[i] = 0;
}

__global__ __launch_bounds__(256) void decode_k(const float* __restrict__ scores,
                                                const float* __restrict__ regs,
                                                float* cand_s, float4* cand_b,
                                                int* cand_n, int* meta) {
  int n = blockIdx.x * 256 + threadIdx.x;
  if (n >= N_ANCH) return;
  int lvl = 0;
  if (n >= 57600) lvl = 1;
  if (n >= 72000) lvl = 2;
  if (n >= 75600) lvl = 3;
  if (n >= 76500) lvl = 4;
  const int aoff = pick5(lvl, 0, 57600, 72000, 75600, 76500);
  const int W = 80 >> lvl;
  int r = n - aoff;
  int a = r % 9;
  int cell = r / 9;
  int x = cell % W, y = cell / W;
  double stride = (double)(8 << lvl);
  double base = (double)(32 << lvl);
  int si = a % 3, ri = a / 3;
  double s = (si == 0) ? 1.0 : (si == 1) ? 1.2599210498948731648 : 1.5874010519681994748;
  double ratio = (ri == 0) ? 0.5 : (ri == 1) ? 1.0 : 2.0;
  double ws0 = base * s;
  double area = ws0 * ws0;
  double w = sqrt(area / ratio);
  double h = w * ratio;
  double cx = ((double)x + 0.5) * stride;
  double cy = ((double)y + 0.5) * stride;
  float ax1 = (float)(cx - 0.5 * w);
  float ay1 = (float)(cy - 0.5 * h);
  float ax2 = (float)(cx + (w - 0.5 * w));
  float ay2 = (float)(cy + (h - 0.5 * h));
  float4 rg = ((const float4*)regs)[n];
  float aw = ax2 - ax1, ah = ay2 - ay1;
  float acx = ax1 + 0.5f * aw, acy = ay1 + 0.5f * ah;
  float pcx = acx + rg.x * 0.1f * aw;
  float pcy = acy + rg.y * 0.1f * ah;
  float pw = expf(rg.z * 0.2f) * aw;
  float ph = expf(rg.w * 0.2f) * ah;
  float x1 = pcx - 0.5f * pw, y1 = pcy - 0.5f * ph;
  float x2 = pcx + 0.5f * pw, y2 = pcy + 0.5f * ph;
  x1 = fminf(fmaxf(x1, 0.f), 640.f);
  y1 = fminf(fmaxf(y1, 0.f), 640.f);
  x2 = fminf(fmaxf(x2, 0.f), 640.f);
  y2 = fminf(fmaxf(y2, 0.f), 640.f);
  float sc = scores[n];
  if (sc > 0.05f) {
    int p = atomicAdd(&meta[0], 1);
    cand_s[p] = sc;
    cand_b[p] = make_float4(x1, y1, x2, y2);
    cand_n[p] = n;
    unsigned int sb = __float_as_uint(sc);
    int bk = (int)(sb >> 16) - (int)BBASE;
    bk = max(0, min(NBKT - 1, bk));
    atomicAdd(&meta[1 + bk], 1);
  }
}

// ---------------- sort-based exact greedy NMS (unchanged from R10) ----------------
__global__ __launch_bounds__(1024) void nms2_k(const float* __restrict__ cs,
                                               const float4* __restrict__ cb,
                                               const int* __restrict__ cn,
                                               const int* __restrict__ meta,
                                               float* __restrict__ out) {
  __shared__ unsigned long long skey[SORT_N];
  __shared__ int sidx[SORT_N];
  __shared__ int suf[NBKT];
  __shared__ float kx1[300], ky1[300], kx2[300], ky2[300], kar[300];
  __shared__ int sh_i[8];
  const int tid = threadIdx.x;
  const int m = min(meta[0], N_ANCH);

  for (int b = tid; b < NBKT; b += 1024) suf[b] = meta[1 + b];
  __syncthreads();
  for (int off = 1; off < NBKT; off <<= 1) {
    int v0 = suf[tid] + ((tid + off < NBKT) ? suf[tid + off] : 0);
    __syncthreads();
    suf[tid] = v0;
    __syncthreads();
  }

  int nk = 0;
  unsigned long long hi64 = ~0ULL;
  int processed = 0;

  while (nk < 300 && processed < m) {
    int base = 0;
    if (hi64 != ~0ULL) {
      if (tid == 0) sh_i[4] = 0;
      __syncthreads();
      int c = 0;
      for (int j = tid; j < m; j += 1024) {
        unsigned long long K = ((unsigned long long)__float_as_uint(cs[j]) << 32) |
                               (unsigned int)(~cn[j]);
        if (K >= hi64) c++;
      }
      atomicAdd(&sh_i[4], c);
      __syncthreads();
      base = sh_i[4];
      __syncthreads();
    }
    if (tid == 0) sh_i[3] = NBKT + 1;
    __syncthreads();
    {
      int T = tid;
      unsigned long long lo =
          (T == 0) ? 0ULL : ((unsigned long long)(((unsigned)T + BBASE) << 16) << 32);
      int c = suf[T] - base;
      if (lo < hi64 && c >= 1 && c <= SORT_N) atomicMin(&sh_i[3], T);
    }
    __syncthreads();
    int T = sh_i[3];
    __syncthreads();
    unsigned long long lo64;
    if (T <= NBKT) {
      lo64 = (T == 0) ? 0ULL : ((unsigned long long)(((unsigned)T + BBASE) << 16) << 32);
    } else {
      unsigned long long L = 0, H = hi64;
      while (H - L > 1) {
        unsigned long long mid = L + ((H - L) >> 1);
        if (tid == 0) sh_i[4] = 0;
        __syncthreads();
        int c = 0;
        for (int j = tid; j < m; j += 1024) {
          unsigned long long K = ((unsigned long long)__float_as_uint(cs[j]) << 32) |
                                 (unsigned int)(~cn[j]);
          if (K >= mid && K < hi64) c++;
        }
        atomicAdd(&sh_i[4], c);
        __syncthreads();
        int cc = sh_i[4];
        __syncthreads();
        if (cc > SORT_N) L = mid; else H = mid;
      }
      lo64 = H;
    }
    if (tid == 0) sh_i[0] = 0;
    __syncthreads();
    for (int j = tid; j < m; j += 1024) {
      unsigned long long K = ((unsigned long long)__float_as_uint(cs[j]) << 32) |
                             (unsigned int)(~cn[j]);
      if (K >= lo64 && K < hi64) {
        int p = atomicAdd(&sh_i[0], 1);
        if (p < SORT_N) { skey[p] = K; sidx[p] = j; }
      }
    }
    __syncthreads();
    int bn = min(sh_i[0], SORT_N);
    __syncthreads();
    for (int p = bn + tid; p < SORT_N; p += 1024) { skey[p] = 0; sidx[p] = 0; }
    __syncthreads();
    for (int k = 2; k <= SORT_N; k <<= 1) {
      for (int jj = k >> 1; jj > 0; jj >>= 1) {
        for (int i = tid; i < SORT_N; i += 1024) {
          int l2 = i ^ jj;
          if (l2 > i) {
            unsigned long long a = skey[i], b2 = skey[l2];
            bool desc = ((i & k) == 0);
            if ((a < b2) == desc) {
              skey[i] = b2; skey[l2] = a;
              int t2 = sidx[i]; sidx[i] = sidx[l2]; sidx[l2] = t2;
            }
          }
        }
        __syncthreads();
      }
    }
    float4 pb0 = (bn > 0) ? cb[sidx[0]] : make_float4(0.f, 0.f, 0.f, 0.f);
    float4 pb1 = (bn > 1) ? cb[sidx[1]] : make_float4(0.f, 0.f, 0.f, 0.f);
    int pos = 0;
    while (pos < bn && nk < 300) {
      float4 c0 = pb0, c1 = pb1;
      const bool has1 = (pos + 1 < bn);
      unsigned long long K0 = skey[pos];
      unsigned long long K1 = has1 ? skey[pos + 1] : 0ULL;
      if (pos + 2 < bn) pb0 = cb[sidx[pos + 2]];
      if (pos + 3 < bn) pb1 = cb[sidx[pos + 3]];
      if (tid == 0) { sh_i[1] = 0; sh_i[2] = 0; }
      __syncthreads();
      float ar0 = (c0.z - c0.x) * (c0.w - c0.y);
      float ar1 = (c1.z - c1.x) * (c1.w - c1.y);
      if (tid < nk) {
        float qx1 = kx1[tid], qy1 = ky1[tid], qx2 = kx2[tid], qy2 = ky2[tid], qa = kar[tid];
        float xx1 = fmaxf(qx1, c0.x), yy1 = fmaxf(qy1, c0.y);
        float xx2 = fminf(qx2, c0.z), yy2 = fminf(qy2, c0.w);
        float inter = fmaxf(xx2 - xx1, 0.f) * fmaxf(yy2 - yy1, 0.f);
        if (inter / (ar0 + qa - inter + 1e-8f) > 0.5f) sh_i[1] = 1;
        if (has1) {
          float ux1 = fmaxf(qx1, c1.x), uy1 = fmaxf(qy1, c1.y);
          float ux2 = fminf(qx2, c1.z), uy2 = fminf(qy2, c1.w);
          float inter1 = fmaxf(ux2 - ux1, 0.f) * fmaxf(uy2 - uy1, 0.f);
          if (inter1 / (ar1 + qa - inter1 + 1e-8f) > 0.5f) sh_i[2] = 1;
        }
      }
      __syncthreads();
      bool k0 = (sh_i[1] == 0);
      float px1 = fmaxf(c0.x, c1.x), py1 = fmaxf(c0.y, c1.y);
      float px2 = fminf(c0.z, c1.z), py2 = fminf(c0.w, c1.w);
      float pint = fmaxf(px2 - px1, 0.f) * fmaxf(py2 - py1, 0.f);
      bool p01 = (pint / (ar1 + ar0 - pint + 1e-8f)) > 0.5f;
      bool k1 = has1 && (sh_i[2] == 0) && !(k0 && p01);
      if (k0) {
        if (tid == 0) {
          kx1[nk] = c0.x; ky1[nk] = c0.y; kx2[nk] = c0.z; ky2[nk] = c0.w; kar[nk] = ar0;
          out[nk] = __uint_as_float((unsigned int)(K0 >> 32));
          out[300 + nk] = 0.0f;
          out[600 + 4 * nk + 0] = c0.x;
          out[600 + 4 * nk + 1] = c0.y;
          out[600 + 4 * nk + 2] = c0.z;
          out[600 + 4 * nk + 3] = c0.w;
        }
        nk++;
      }
      if (nk < 300 && k1) {
        if (tid == 0) {
          kx1[nk] = c1.x; ky1[nk] = c1.y; kx2[nk] = c1.z; ky2[nk] = c1.w; kar[nk] = ar1;
          out[nk] = __uint_as_float((unsigned int)(K1 >> 32));
          out[300 + nk] = 0.0f;
          out[600 + 4 * nk + 0] = c1.x;
          out[600 + 4 * nk + 1] = c1.y;
          out[600 + 4 * nk + 2] = c1.z;
          out[600 + 4 * nk + 3] = c1.w;
        }
        nk++;
      }
      pos += 2;
    }
    processed = base + bn;
    hi64 = lo64;
  }
  __syncthreads();
  for (int r = nk + tid; r < 300; r += 1024) {
    out[r] = 0.f;
    out[300 + r] = -1.f;
    out[600 + 4 * r + 0] = 0.f;
    out[600 + 4 * r + 1] = 0.f;
    out[600 + 4 * r + 2] = 0.f;
    out[600 + 4 * r + 3] = 0.f;
  }
}

// ---------------- host ----------------
extern "C" void kernel_launch(void* const* d_in, const int* in_sizes, int n_in,
                              void* d_out, int out_size, void* d_ws, size_t ws_size,
                              hipStream_t stream) {
  (void)in_sizes; (void)n_in; (void)out_size; (void)ws_size;
  const float* feats[5];
  for (int l = 0; l < 5; l++) feats[l] = (const float*)d_in[1 + l];
  const float* cls_w = (const float*)d_in[6];
  const float* cls_b = (const float*)d_in[7];
  const float* cls_ow = (const float*)d_in[8];
  const float* cls_ob = (const float*)d_in[9];
  const float* reg_w = (const float*)d_in[10];
  const float* reg_b = (const float*)d_in[11];
  const float* reg_ow = (const float*)d_in[12];
  const float* reg_ob = (const float*)d_in[13];

  static const int AOFF[5] = {0, 1638400, 2048000, 2150400, 2176000}; // 256*cumHW
  const size_t ACT = 2182400;  // 256*8525 floats per head

  float* ws = (float*)d_ws;
  float* bufA = ws;                       // 2*ACT
  float* bufB = bufA + 2 * ACT;           // 2*ACT
  float* scores = bufB + 2 * ACT;         // 76736 (padded)
  float* regs = scores + 76736;           // 306912 (padded)
  float* cand_s = regs + 306912;          // 76736
  float* cand_b = cand_s + 76736;         // 306944
  int* cand_n = (int*)(cand_b + 306944);  // 76736 ints
  int* meta = cand_n + 76736;             // [0]=cnt, [1..NBKT]=hist
  float* wt = (float*)(meta + 1032);      // 2 heads x 4 cog x 2304 x 64
  float* wt2o = wt + 2 * 4 * 2304 * 64;   // 5 x 2304 x 16

  float* bufs[2] = {bufA, bufB};
  TrunkArgs ta;
  WtrArgs wa;
  wa.dst = wt;
  wtro_k<<<dim3(9), dim3(256), 0, stream>>>(cls_ow, reg_ow, wt2o);
  for (int layer = 0; layer < 4; layer++) {
    wa.src[0] = cls_w + (size_t)layer * 589824;
    wa.src[1] = reg_w + (size_t)layer * 589824;
    wtr_k<<<dim3(32, 4, 2), dim3(256), 0, stream>>>(wa);
    for (int h = 0; h < 2; h++) {
      ta.w[h] = wt + (size_t)h * 4 * 2304 * 64;
      ta.b[h] = (h ? reg_b : cls_b) + layer * 256;
      for (int l = 0; l < 5; l++) {
        ta.out[h][l] = bufs[layer & 1] + h * ACT + AOFF[l];
        ta.in[h][l] = (layer == 0) ? feats[l] : (const float*)(bufs[(layer - 1) & 1] + h * ACT + AOFF[l]);
      }
    }
    conv_trunk<<<dim3(74, 4, 2), dim3(256), 0, stream>>>(ta);
  }

  Out2Args oa;
  for (int l = 0; l < 5; l++) {
    oa.in[0][l] = bufB + 0 * ACT + AOFF[l];
    oa.in[1][l] = bufB + 1 * ACT + AOFF[l];
  }
  oa.w = wt2o;
  oa.b[0] = cls_ob; oa.b[1] = reg_ob;
  oa.dst[0] = scores; oa.dst[1] = regs;
  conv_out2<<<dim3(139, 5), dim3(192), 0, stream>>>(oa);

  init_k<<<dim3(5), dim3(256), 0, stream>>>(meta);
  decode_k<<<dim3((N_ANCH + 255) / 256), dim3(256), 0, stream>>>(scores, regs, cand_s,
                                                                 (float4*)cand_b, cand_n, meta);
  nms2_k<<<dim3(1), dim3(1024), 0, stream>>>(cand_s, (const float4*)cand_b, cand_n, meta,
                                             (float*)d_out);
}